// Round 1
// baseline (85.815 us; speedup 1.0000x reference)
//
#include <hip/hip_runtime.h>
#include <hip/hip_bf16.h>

typedef __bf16 bf16x8 __attribute__((ext_vector_type(8)));
typedef float  f32x4  __attribute__((ext_vector_type(4)));

#define IN_F   4096
#define OUT_F  4096
#define RANK   32
#define BM     16
#define NTHR   256

__device__ __forceinline__ bf16x8 cvt8(float4 a, float4 b) {
    bf16x8 r;
    r[0] = (__bf16)a.x; r[1] = (__bf16)a.y; r[2] = (__bf16)a.z; r[3] = (__bf16)a.w;
    r[4] = (__bf16)b.x; r[5] = (__bf16)b.y; r[6] = (__bf16)b.z; r[7] = (__bf16)b.w;
    return r;
}

__global__ __launch_bounds__(NTHR, 2)
void lora_fused(const float* __restrict__ X, const float* __restrict__ U,
                const float* __restrict__ S, const float* __restrict__ V,
                float* __restrict__ Out)
{
    __shared__ float Hp[4][BM][RANK];      // per-wave K-partial H
    __shared__ float Hs[BM][RANK + 4];     // reduced H, padded stride 36 (2-way LDS max)

    const int tid  = threadIdx.x;
    const int wave = tid >> 6;             // 0..3
    const int lane = tid & 63;
    const int row  = lane & 15;            // MFMA row / col index
    const int kg   = lane >> 4;            // 0..3 k-group

    const int t0 = blockIdx.x * BM;        // first token of this block

    // ---------- Stage 1: H_partial = X_tile @ V^T over this wave's K quarter ----------
    f32x4 acc0 = {0.f, 0.f, 0.f, 0.f};
    f32x4 acc1 = {0.f, 0.f, 0.f, 0.f};

    const float* xptr  = X + (size_t)(t0 + row) * IN_F + wave * (IN_F / 4) + kg * 8;
    const float* v0ptr = V + (size_t)row        * IN_F + wave * (IN_F / 4) + kg * 8;
    const float* v1ptr = V + (size_t)(16 + row) * IN_F + wave * (IN_F / 4) + kg * 8;

    #pragma unroll 2
    for (int ks = 0; ks < 32; ++ks) {      // 32 steps x K=32 = 1024 features
        const float4* ap  = reinterpret_cast<const float4*>(xptr  + ks * 32);
        const float4* b0p = reinterpret_cast<const float4*>(v0ptr + ks * 32);
        const float4* b1p = reinterpret_cast<const float4*>(v1ptr + ks * 32);
        float4 a0 = ap[0],  a1 = ap[1];
        float4 c0 = b0p[0], c1 = b0p[1];
        float4 d0 = b1p[0], d1 = b1p[1];
        bf16x8 af  = cvt8(a0, a1);
        bf16x8 bf0 = cvt8(c0, c1);
        bf16x8 bf1 = cvt8(d0, d1);
        acc0 = __builtin_amdgcn_mfma_f32_16x16x32_bf16(af, bf0, acc0, 0, 0, 0);
        acc1 = __builtin_amdgcn_mfma_f32_16x16x32_bf16(af, bf1, acc1, 0, 0, 0);
    }

    // D layout (verified m89): col = lane&15 (rank), row = kg*4+j (token)
    #pragma unroll
    for (int j = 0; j < 4; ++j) {
        Hp[wave][kg * 4 + j][row]      = acc0[j];
        Hp[wave][kg * 4 + j][16 + row] = acc1[j];
    }
    __syncthreads();

    // reduce the 4 K-partials, apply S
    for (int i = tid; i < BM * RANK; i += NTHR) {
        int tok = i >> 5, r = i & 31;
        float s = Hp[0][tok][r] + Hp[1][tok][r] + Hp[2][tok][r] + Hp[3][tok][r];
        Hs[tok][r] = s * S[r];             // SCALING == 1.0, folded out
    }
    __syncthreads();

    // ---------- Stage 2: Out_tile = H @ U^T (K = RANK = 32, one MFMA per 16x16 tile) ----------
    bf16x8 ha;
    #pragma unroll
    for (int j = 0; j < 8; ++j) ha[j] = (__bf16)Hs[row][kg * 8 + j];

    float* obase = Out + (size_t)(t0 + kg * 4) * OUT_F + row;

    #pragma unroll 4
    for (int i = 0; i < 64; ++i) {
        int o0 = (i * 4 + wave) * 16;      // waves interleave n-tiles for store adjacency
        const float4* up = reinterpret_cast<const float4*>(
            U + (size_t)(o0 + row) * RANK + kg * 8);
        float4 u0 = up[0], u1 = up[1];
        bf16x8 bu = cvt8(u0, u1);
        f32x4 d = {0.f, 0.f, 0.f, 0.f};
        d = __builtin_amdgcn_mfma_f32_16x16x32_bf16(ha, bu, d, 0, 0, 0);
        #pragma unroll
        for (int j = 0; j < 4; ++j)
            obase[(size_t)j * OUT_F + o0] = d[j];
    }
}

extern "C" void kernel_launch(void* const* d_in, const int* in_sizes, int n_in,
                              void* d_out, int out_size, void* d_ws, size_t ws_size,
                              hipStream_t stream) {
    const float* X = (const float*)d_in[0];
    const float* U = (const float*)d_in[1];
    const float* S = (const float*)d_in[2];
    const float* V = (const float*)d_in[3];
    float* Out = (float*)d_out;

    dim3 grid(8192 / BM);   // 512 blocks, 256 threads, 2 blocks/CU
    lora_fused<<<grid, NTHR, 0, stream>>>(X, U, S, V, Out);
}